// Round 3
// baseline (4256.510 us; speedup 1.0000x reference)
//
#include <hip/hip_runtime.h>
#include <hip/hip_fp16.h>
#include <cstdint>
#include <cstddef>

typedef _Float16 half_t;
typedef _Float16 half2_t __attribute__((ext_vector_type(2)));
typedef _Float16 half8_t __attribute__((ext_vector_type(8)));
typedef float    f32x4   __attribute__((ext_vector_type(4)));
typedef unsigned int uint4v __attribute__((ext_vector_type(4)));

#define T_FULL  2048
#define T_CH    512
#define N_CHUNK 4
#define B_SZ    64
#define H_SZ    256
#define G4      1024
#define CH_M    (B_SZ * T_CH)   // 32768

// Per hh-half (64 k-pairs): 36 pinned in VGPRs, 16 in LDS, 12 streamed from L1/L2
#define KP_RF   36
#define KP_LDS  16
#define KP_STR  12

// ---------------- workspace layout (bytes) ----------------
static constexpr size_t OFF_XW   = 0;                                   // half [CH_M][1024] (i,f,g,o)x256
static constexpr size_t OFF_H    = OFF_XW   + (size_t)CH_M * G4 * 2;    // half [CH_M][256]
static constexpr size_t OFF_WIH  = OFF_H    + (size_t)CH_M * H_SZ * 2;  // half [1024][256]  (B^T)
static constexpr size_t OFF_WOUT = OFF_WIH  + (size_t)G4 * 256 * 2;     // half [256][256]   (B^T)
static constexpr size_t OFF_WRF  = OFF_WOUT + (size_t)256 * 256 * 2;    // uint4 [2][36][256]
static constexpr size_t OFF_WLDS = OFF_WRF  + (size_t)2 * KP_RF * 256 * 16;  // uint4 [2][16][256]
static constexpr size_t OFF_WSTR = OFF_WLDS + (size_t)2 * KP_LDS * 256 * 16; // uint4 [2][256][12]
static constexpr size_t OFF_SC   = OFF_WSTR + (size_t)2 * 256 * KP_STR * 16; // float [64][256]
static constexpr size_t OFF_SH   = OFF_SC   + (size_t)B_SZ * H_SZ * 4;  // uint [64][128] f16 pairs

// ---------------- helpers ----------------
__device__ __forceinline__ unsigned int packh2(float a, float b) {
    half2_t h; h.x = (half_t)a; h.y = (half_t)b;
    return __builtin_bit_cast(unsigned int, h);
}

__device__ __forceinline__ float dot2f(unsigned int hp, unsigned int wp, float acc) {
#if __has_builtin(__builtin_amdgcn_fdot2)
    return __builtin_amdgcn_fdot2(__builtin_bit_cast(half2_t, hp),
                                  __builtin_bit_cast(half2_t, wp), acc, false);
#else
    half2_t h = __builtin_bit_cast(half2_t, hp);
    half2_t w = __builtin_bit_cast(half2_t, wp);
    return fmaf((float)h.y, (float)w.y, fmaf((float)h.x, (float)w.x, acc));
#endif
}

__device__ __forceinline__ unsigned int rlane(unsigned int v, int lane) {
    return (unsigned int)__builtin_amdgcn_readlane((int)v, lane);
}

__device__ __forceinline__ float sigm(float x)  { return 1.0f / (1.0f + __expf(-x)); }
__device__ __forceinline__ float tanh_(float x) { return 1.0f - 2.0f / (__expf(2.0f * x) + 1.0f); }

// ---------------- K0: pack weights + init state ----------------
// word sections: wih 262144 | wout 65536 | rf 73728 | lds 32768 | str 24576 | c 16384 | h 8192
static constexpr int PACK_TOTAL = 262144 + 65536
                                + 2 * KP_RF  * 256 * 4
                                + 2 * KP_LDS * 256 * 4
                                + 2 * KP_STR * 256 * 4
                                + 16384 + 8192;

__global__ __launch_bounds__(256) void pack_kernel(
    const float* __restrict__ Wih, const float* __restrict__ Whh,
    const float* __restrict__ Wout, const float* __restrict__ c0,
    const float* __restrict__ h0,
    half_t* __restrict__ wih_t, half_t* __restrict__ wout_t,
    unsigned int* __restrict__ whh_rf, unsigned int* __restrict__ whh_lds,
    unsigned int* __restrict__ whh_str,
    float* __restrict__ state_c, unsigned int* __restrict__ state_h)
{
    const int stride = gridDim.x * blockDim.x;
    for (int idx = blockIdx.x * blockDim.x + threadIdx.x; idx < PACK_TOTAL; idx += stride) {
        int r = idx;
        if (r < 262144) {                       // wih_t[n][k] = Wih[k][n]
            int n = r >> 8, k = r & 255;
            wih_t[r] = (half_t)Wih[k * 1024 + n];
            continue;
        }
        r -= 262144;
        if (r < 65536) {                        // wout_t[n][k] = Wout[k][n]
            int n = r >> 8, k = r & 255;
            wout_t[r] = (half_t)Wout[k * 256 + n];
            continue;
        }
        r -= 65536;
        if (r < 2 * KP_RF * 256 * 4) {          // rf: uint4[hh][pl][e], component j = gate
            int j = r & 3, e = (r >> 2) & 255, q = r >> 10;
            int pl = q % KP_RF, hh = q / KP_RF;
            int k0 = 2 * (hh * 64 + pl);
            int col = j * 256 + e;
            whh_rf[r] = packh2(Whh[k0 * 1024 + col], Whh[(k0 + 1) * 1024 + col]);
            continue;
        }
        r -= 2 * KP_RF * 256 * 4;
        if (r < 2 * KP_LDS * 256 * 4) {         // lds: uint4[hh][ql][e], pairs 36..51
            int j = r & 3, e = (r >> 2) & 255, q = r >> 10;
            int ql = q % KP_LDS, hh = q / KP_LDS;
            int k0 = 2 * (hh * 64 + KP_RF + ql);
            int col = j * 256 + e;
            whh_lds[r] = packh2(Whh[k0 * 1024 + col], Whh[(k0 + 1) * 1024 + col]);
            continue;
        }
        r -= 2 * KP_LDS * 256 * 4;
        if (r < 2 * KP_STR * 256 * 4) {         // str: uint4[hh][e][sl], pairs 52..63 (thread-contiguous)
            int j = r & 3, q = r >> 2;
            int sl = q % KP_STR, t2 = q / KP_STR;
            int e = t2 & 255, hh = t2 >> 8;
            int k0 = 2 * (hh * 64 + KP_RF + KP_LDS + sl);
            int col = j * 256 + e;
            whh_str[r] = packh2(Whh[k0 * 1024 + col], Whh[(k0 + 1) * 1024 + col]);
            continue;
        }
        r -= 2 * KP_STR * 256 * 4;
        if (r < 16384) { state_c[r] = c0[r]; continue; }
        r -= 16384;
        state_h[r] = packh2(h0[2 * r], h0[2 * r + 1]);
    }
}

// ---------------- K1/K3: f16 MFMA GEMM, 128x128 tile, K=256 ----------------
template<int AMODE, int CMODE>
__global__ __launch_bounds__(256) void gemm16(
    const void* __restrict__ Ap, const half_t* __restrict__ Bt,
    void* __restrict__ Cp, const float* __restrict__ bias, int chunk0)
{
    __shared__ half_t Als[128][40];
    __shared__ half_t Bls[128][40];
    const int tid  = threadIdx.x;
    const int lane = tid & 63, wid = tid >> 6;
    const int wr = wid >> 1, wc = wid & 1;
    const int m0 = blockIdx.x * 128, n0 = blockIdx.y * 128;

    f32x4 acc[4][4] = {};

    for (int kc = 0; kc < 8; ++kc) {
        __syncthreads();
        if (AMODE == 1) {
            const float* A = (const float*)Ap;
            #pragma unroll
            for (int i = 0; i < 4; ++i) {
                int l = tid + i * 256;
                int row = l >> 3, kq = l & 7;
                int m = m0 + row;
                int arow = ((m >> 9) << 11) + chunk0 + (m & 511);
                f32x4 v = *(const f32x4*)(A + (size_t)arow * 256 + kc * 32 + kq * 4);
                uint2 pk;
                pk.x = packh2(v.x, v.y);
                pk.y = packh2(v.z, v.w);
                *reinterpret_cast<uint2*>(&Als[row][kq * 4]) = pk;
            }
        } else {
            const half_t* A = (const half_t*)Ap;
            #pragma unroll
            for (int i = 0; i < 2; ++i) {
                int l = tid + i * 256;
                int row = l >> 2, ko = l & 3;
                half8_t v = *(const half8_t*)(A + (size_t)(m0 + row) * 256 + kc * 32 + ko * 8);
                *reinterpret_cast<half8_t*>(&Als[row][ko * 8]) = v;
            }
        }
        #pragma unroll
        for (int i = 0; i < 2; ++i) {
            int l = tid + i * 256;
            int row = l >> 2, ko = l & 3;
            half8_t v = *(const half8_t*)(Bt + (size_t)(n0 + row) * 256 + kc * 32 + ko * 8);
            *reinterpret_cast<half8_t*>(&Bls[row][ko * 8]) = v;
        }
        __syncthreads();

        half8_t af[4], bf[4];
        #pragma unroll
        for (int mi = 0; mi < 4; ++mi)
            af[mi] = *reinterpret_cast<const half8_t*>(&Als[wr * 64 + mi * 16 + (lane & 15)][(lane >> 4) * 8]);
        #pragma unroll
        for (int ni = 0; ni < 4; ++ni)
            bf[ni] = *reinterpret_cast<const half8_t*>(&Bls[wc * 64 + ni * 16 + (lane & 15)][(lane >> 4) * 8]);
        #pragma unroll
        for (int mi = 0; mi < 4; ++mi)
            #pragma unroll
            for (int ni = 0; ni < 4; ++ni)
                acc[mi][ni] = __builtin_amdgcn_mfma_f32_16x16x32_f16(af[mi], bf[ni], acc[mi][ni], 0, 0, 0);
    }

    #pragma unroll
    for (int mi = 0; mi < 4; ++mi) {
        #pragma unroll
        for (int ni = 0; ni < 4; ++ni) {
            #pragma unroll
            for (int reg = 0; reg < 4; ++reg) {
                int row = m0 + wr * 64 + mi * 16 + (lane >> 4) * 4 + reg;   // m
                int col = n0 + wc * 64 + ni * 16 + (lane & 15);             // n
                float v = acc[mi][ni][reg] + bias[col];
                if (CMODE == 0) {
                    ((half_t*)Cp)[(size_t)row * 1024 + ((col & 255) << 2) + (col >> 8)] = (half_t)v;
                } else {
                    int crow = ((row >> 9) << 11) + chunk0 + (row & 511);
                    ((float*)Cp)[(size_t)crow * 256 + col] = v;
                }
            }
        }
    }
}

// ---------------- K2: per-chain recurrent LSTM, K-split across 512 threads ----------------
// thread (e = t&255, hh = t>>8): all 4 gate cols of element e, k-half hh.
// 36 weight uint4s in arch VGPRs (amdgpu_waves_per_eu(2,2) grants the 256-VGPR budget;
// demand ~225 leaves headroom so the allocator keeps them resident), 16 pairs in LDS
// (LDS pipe overlaps VALU), 12 streamed thread-contiguous (1 base addr, L1-line reuse).
#define W_A(F) F(0) F(1) F(2) F(3) F(4) F(5) F(6) F(7) F(8) F(9) F(10) F(11) \
               F(12) F(13) F(14) F(15) F(16) F(17)
#define W_B(F) F(18) F(19) F(20) F(21) F(22) F(23) F(24) F(25) F(26) F(27) F(28) F(29) \
               F(30) F(31) F(32) F(33) F(34) F(35)
#define W_ALL(F) W_A(F) W_B(F)

#define LDW(i)  uint4v w##i = wq[(i) * 256];
#define PINW(i) asm volatile("" : "+v"(w##i));
#define DOTW(i) { unsigned int s = rlane(hv, (i)); \
    a0 = dot2f(s, w##i.x, a0); a1 = dot2f(s, w##i.y, a1); \
    a2 = dot2f(s, w##i.z, a2); a3 = dot2f(s, w##i.w, a3); }
#define DOTQ(i, q) { unsigned int s = rlane(hv, KP_RF + (i)); \
    a0 = dot2f(s, (q).x, a0); a1 = dot2f(s, (q).y, a1); \
    a2 = dot2f(s, (q).z, a2); a3 = dot2f(s, (q).w, a3); }
#define DOTS(i, q) { unsigned int s = rlane(hv, KP_RF + KP_LDS + (i)); \
    a0 = dot2f(s, (q).x, a0); a1 = dot2f(s, (q).y, a1); \
    a2 = dot2f(s, (q).z, a2); a3 = dot2f(s, (q).w, a3); }

__global__
__attribute__((amdgpu_flat_work_group_size(512, 512), amdgpu_waves_per_eu(2, 2)))
void rnn_kernel(
    const uint4v* __restrict__ whh_rf,
    const uint4v* __restrict__ whh_ldsrc,
    const uint4v* __restrict__ whh_str,
    const half_t* __restrict__ xw,
    half_t* __restrict__ h_out,
    float* __restrict__ state_c,
    unsigned int* __restrict__ state_h)
{
    __shared__ uint4v lds_w[2 * KP_LDS * 256];   // 131072 B
    __shared__ f32x4  gbuf[256];                 // 4096 B
    __shared__ unsigned int hbuf[128];           // 512 B

    const int t    = threadIdx.x;
    const int e    = t & 255;
    const int hh   = t >> 8;
    const int lane = t & 63;
    const int b    = blockIdx.x;

    for (int i = t; i < 2 * KP_LDS * 256; i += 512) lds_w[i] = whh_ldsrc[i];
    if (t < 128) hbuf[t] = state_h[b * 128 + t];
    float c = (hh == 0) ? state_c[b * 256 + e] : 0.0f;

    // register-resident Whh: k-pairs (hh*64 + 0..35), one uint4 = 4 gate cols {e,256+e,512+e,768+e}
    const uint4v* wq = whh_rf + (size_t)hh * (KP_RF * 256) + e;
    W_ALL(LDW)
    W_ALL(PINW)
    __syncthreads();

    const half_t* xwp = xw + (size_t)b * T_CH * 1024 + e * 4;
    half_t* hop = h_out + (size_t)b * T_CH * 256 + e;
    const uint4v* strq = whh_str + ((size_t)hh * 256 + e) * KP_STR;   // 12 contiguous quads
    const uint4v* ldp  = lds_w + hh * (KP_LDS * 256) + e;

    for (int step = 0; step < T_CH; ++step) {
        // h broadcast source: pairs hh*64 .. hh*64+63 (one LDS word per lane)
        unsigned int hv = hbuf[hh * 64 + lane];

        uint2 xv; xv.x = 0; xv.y = 0;
        if (hh == 0) xv = *(const uint2*)xwp;

        float a0 = 0.f, a1 = 0.f, a2 = 0.f, a3 = 0.f;

        // ---- batch 1: 8 LDS + 6 streamed quads (56 transient VGPRs) ----
        {
            uint4v q0 = ldp[0],    q1 = ldp[256],  q2 = ldp[512],  q3 = ldp[768];
            uint4v q4 = ldp[1024], q5 = ldp[1280], q6 = ldp[1536], q7 = ldp[1792];
            uint4v t0 = strq[0], t1 = strq[1], t2 = strq[2];
            uint4v t3 = strq[3], t4 = strq[4], t5 = strq[5];

            W_A(DOTW)   // 72 dots cover batch-1 latency

            DOTQ(0, q0) DOTQ(1, q1) DOTQ(2, q2) DOTQ(3, q3)
            DOTQ(4, q4) DOTQ(5, q5) DOTQ(6, q6) DOTQ(7, q7)
            DOTS(0, t0) DOTS(1, t1) DOTS(2, t2)
            DOTS(3, t3) DOTS(4, t4) DOTS(5, t5)
        }

        // ---- batch 2: remaining 8 LDS + 6 streamed quads ----
        {
            uint4v q8  = ldp[2048], q9  = ldp[2304], q10 = ldp[2560], q11 = ldp[2816];
            uint4v q12 = ldp[3072], q13 = ldp[3328], q14 = ldp[3584], q15 = ldp[3840];
            uint4v t6 = strq[6], t7 = strq[7], t8 = strq[8];
            uint4v t9 = strq[9], t10 = strq[10], t11 = strq[11];

            W_B(DOTW)   // 72 dots cover batch-2 latency

            DOTQ(8, q8)   DOTQ(9, q9)   DOTQ(10, q10) DOTQ(11, q11)
            DOTQ(12, q12) DOTQ(13, q13) DOTQ(14, q14) DOTQ(15, q15)
            DOTS(6, t6)   DOTS(7, t7)   DOTS(8, t8)
            DOTS(9, t9)   DOTS(10, t10) DOTS(11, t11)
        }

        if (hh) {
            f32x4 p; p[0] = a0; p[1] = a1; p[2] = a2; p[3] = a3;
            gbuf[e] = p;
        }
        __syncthreads();   // gbuf write -> read; hbuf read -> write

        half_t h16 = (half_t)0.f;
        if (hh == 0) {
            f32x4 p = gbuf[e];
            half2_t x0 = __builtin_bit_cast(half2_t, xv.x);
            half2_t x1 = __builtin_bit_cast(half2_t, xv.y);
            a0 += p[0] + (float)x0.x;
            a1 += p[1] + (float)x0.y;
            a2 += p[2] + (float)x1.x;
            a3 += p[3] + (float)x1.y;
            float ig = sigm(a0), fg = sigm(a1), gg = tanh_(a2), og = sigm(a3);
            c = fg * c + ig * gg;
            float hn = og * tanh_(c);
            h16 = (half_t)hn;
            reinterpret_cast<half_t*>(hbuf)[e] = h16;
        }
        xwp += 1024;
        __syncthreads();   // hbuf write -> next read; gbuf read -> next write

        // deferred global store: drains at NEXT step's first barrier, off the critical path
        if (hh == 0) *hop = h16;
        hop += 256;
    }

    if (hh == 0) state_c[b * 256 + e] = c;
    if (t < 128) state_h[b * 128 + t] = hbuf[t];
}

// ---------------- launch ----------------
extern "C" void kernel_launch(void* const* d_in, const int* in_sizes, int n_in,
                              void* d_out, int out_size, void* d_ws, size_t ws_size,
                              hipStream_t stream) {
    const float* x    = (const float*)d_in[0];
    const float* c0   = (const float*)d_in[1];
    const float* h0   = (const float*)d_in[2];
    const float* Wih  = (const float*)d_in[3];
    const float* Whh  = (const float*)d_in[4];
    const float* bh   = (const float*)d_in[5];
    const float* Wout = (const float*)d_in[6];
    const float* bout = (const float*)d_in[7];

    char* ws = (char*)d_ws;
    half_t* xw             = (half_t*)(ws + OFF_XW);
    half_t* h_chunk        = (half_t*)(ws + OFF_H);
    half_t* wih_t          = (half_t*)(ws + OFF_WIH);
    half_t* wout_t         = (half_t*)(ws + OFF_WOUT);
    unsigned int* whh_rf   = (unsigned int*)(ws + OFF_WRF);
    unsigned int* whh_lds  = (unsigned int*)(ws + OFF_WLDS);
    unsigned int* whh_str  = (unsigned int*)(ws + OFF_WSTR);
    float* state_c         = (float*)(ws + OFF_SC);
    unsigned int* state_h  = (unsigned int*)(ws + OFF_SH);

    pack_kernel<<<512, 256, 0, stream>>>(Wih, Whh, Wout, c0, h0,
                                         wih_t, wout_t, whh_rf, whh_lds, whh_str,
                                         state_c, state_h);

    for (int ch = 0; ch < N_CHUNK; ++ch) {
        int chunk0 = ch * T_CH;
        gemm16<1, 0><<<dim3(CH_M / 128, G4 / 128), 256, 0, stream>>>(
            (const void*)x, wih_t, (void*)xw, bh, chunk0);
        rnn_kernel<<<B_SZ, 512, 0, stream>>>((const uint4v*)(ws + OFF_WRF),
                                             (const uint4v*)(ws + OFF_WLDS),
                                             (const uint4v*)(ws + OFF_WSTR),
                                             xw, h_chunk, state_c, state_h);
        gemm16<0, 1><<<dim3(CH_M / 128, H_SZ / 128), 256, 0, stream>>>(
            (const void*)h_chunk, wout_t, d_out, bout, chunk0);
    }
    (void)in_sizes; (void)n_in; (void)out_size; (void)ws_size;
}

// Round 4
// 4186.984 us; speedup vs baseline: 1.0166x; 1.0166x over previous
//
#include <hip/hip_runtime.h>
#include <hip/hip_fp16.h>
#include <cstdint>
#include <cstddef>

typedef _Float16 half_t;
typedef _Float16 half2_t __attribute__((ext_vector_type(2)));
typedef _Float16 half8_t __attribute__((ext_vector_type(8)));
typedef float    f32x4   __attribute__((ext_vector_type(4)));
typedef unsigned int uint4v __attribute__((ext_vector_type(4)));

#define T_FULL  2048
#define T_CH    512
#define N_CHUNK 4
#define B_SZ    64
#define H_SZ    256
#define G4      1024
#define CH_M    (B_SZ * T_CH)   // 32768

// Per hh-half (64 k-pairs): 36 in VGPRs (plain C, xor-opaqued), 16 in LDS, 12 streamed
#define KP_RF   36
#define KP_LDS  16
#define KP_STR  12

// ---------------- workspace layout (bytes) ----------------
static constexpr size_t OFF_XW   = 0;                                   // half [CH_M][1024] (i,f,g,o)x256
static constexpr size_t OFF_H    = OFF_XW   + (size_t)CH_M * G4 * 2;    // half [CH_M][256]
static constexpr size_t OFF_WIH  = OFF_H    + (size_t)CH_M * H_SZ * 2;  // half [1024][256]  (B^T)
static constexpr size_t OFF_WOUT = OFF_WIH  + (size_t)G4 * 256 * 2;     // half [256][256]   (B^T)
static constexpr size_t OFF_WRF  = OFF_WOUT + (size_t)256 * 256 * 2;    // uint4 [2][36][256]
static constexpr size_t OFF_WLDS = OFF_WRF  + (size_t)2 * KP_RF * 256 * 16;  // uint4 [2][16][256]
static constexpr size_t OFF_WSTR = OFF_WLDS + (size_t)2 * KP_LDS * 256 * 16; // uint4 [2][256][12]
static constexpr size_t OFF_SC   = OFF_WSTR + (size_t)2 * 256 * KP_STR * 16; // float [64][256]
static constexpr size_t OFF_SH   = OFF_SC   + (size_t)B_SZ * H_SZ * 4;  // uint [64][128] f16 pairs
static constexpr size_t OFF_Z    = OFF_SH   + (size_t)B_SZ * 128 * 4;   // uint4 zero quad (runtime-opaque)

// ---------------- helpers ----------------
__device__ __forceinline__ unsigned int packh2(float a, float b) {
    half2_t h; h.x = (half_t)a; h.y = (half_t)b;
    return __builtin_bit_cast(unsigned int, h);
}

__device__ __forceinline__ float dot2f(unsigned int hp, unsigned int wp, float acc) {
#if __has_builtin(__builtin_amdgcn_fdot2)
    return __builtin_amdgcn_fdot2(__builtin_bit_cast(half2_t, hp),
                                  __builtin_bit_cast(half2_t, wp), acc, false);
#else
    half2_t h = __builtin_bit_cast(half2_t, hp);
    half2_t w = __builtin_bit_cast(half2_t, wp);
    return fmaf((float)h.y, (float)w.y, fmaf((float)h.x, (float)w.x, acc));
#endif
}

__device__ __forceinline__ unsigned int rlane(unsigned int v, int lane) {
    return (unsigned int)__builtin_amdgcn_readlane((int)v, lane);
}

__device__ __forceinline__ float sigm(float x)  { return 1.0f / (1.0f + __expf(-x)); }
__device__ __forceinline__ float tanh_(float x) { return 1.0f - 2.0f / (__expf(2.0f * x) + 1.0f); }

// ---------------- K0: pack weights + init state ----------------
// word sections: wih 262144 | wout 65536 | rf 73728 | lds 32768 | str 24576 | c 16384 | h 8192 | z 4
static constexpr int PACK_TOTAL = 262144 + 65536
                                + 2 * KP_RF  * 256 * 4
                                + 2 * KP_LDS * 256 * 4
                                + 2 * KP_STR * 256 * 4
                                + 16384 + 8192 + 4;

__global__ __launch_bounds__(256) void pack_kernel(
    const float* __restrict__ Wih, const float* __restrict__ Whh,
    const float* __restrict__ Wout, const float* __restrict__ c0,
    const float* __restrict__ h0,
    half_t* __restrict__ wih_t, half_t* __restrict__ wout_t,
    unsigned int* __restrict__ whh_rf, unsigned int* __restrict__ whh_lds,
    unsigned int* __restrict__ whh_str,
    float* __restrict__ state_c, unsigned int* __restrict__ state_h,
    unsigned int* __restrict__ zpad)
{
    const int stride = gridDim.x * blockDim.x;
    for (int idx = blockIdx.x * blockDim.x + threadIdx.x; idx < PACK_TOTAL; idx += stride) {
        int r = idx;
        if (r < 262144) {                       // wih_t[n][k] = Wih[k][n]
            int n = r >> 8, k = r & 255;
            wih_t[r] = (half_t)Wih[k * 1024 + n];
            continue;
        }
        r -= 262144;
        if (r < 65536) {                        // wout_t[n][k] = Wout[k][n]
            int n = r >> 8, k = r & 255;
            wout_t[r] = (half_t)Wout[k * 256 + n];
            continue;
        }
        r -= 65536;
        if (r < 2 * KP_RF * 256 * 4) {          // rf: uint4[hh][pl][e], component j = gate
            int j = r & 3, e = (r >> 2) & 255, q = r >> 10;
            int pl = q % KP_RF, hh = q / KP_RF;
            int k0 = 2 * (hh * 64 + pl);
            int col = j * 256 + e;
            whh_rf[r] = packh2(Whh[k0 * 1024 + col], Whh[(k0 + 1) * 1024 + col]);
            continue;
        }
        r -= 2 * KP_RF * 256 * 4;
        if (r < 2 * KP_LDS * 256 * 4) {         // lds: uint4[hh][ql][e], pairs 36..51
            int j = r & 3, e = (r >> 2) & 255, q = r >> 10;
            int ql = q % KP_LDS, hh = q / KP_LDS;
            int k0 = 2 * (hh * 64 + KP_RF + ql);
            int col = j * 256 + e;
            whh_lds[r] = packh2(Whh[k0 * 1024 + col], Whh[(k0 + 1) * 1024 + col]);
            continue;
        }
        r -= 2 * KP_LDS * 256 * 4;
        if (r < 2 * KP_STR * 256 * 4) {         // str: uint4[hh][e][sl], pairs 52..63 (thread-contiguous)
            int j = r & 3, q = r >> 2;
            int sl = q % KP_STR, t2 = q / KP_STR;
            int e = t2 & 255, hh = t2 >> 8;
            int k0 = 2 * (hh * 64 + KP_RF + KP_LDS + sl);
            int col = j * 256 + e;
            whh_str[r] = packh2(Whh[k0 * 1024 + col], Whh[(k0 + 1) * 1024 + col]);
            continue;
        }
        r -= 2 * KP_STR * 256 * 4;
        if (r < 16384) { state_c[r] = c0[r]; continue; }
        r -= 16384;
        if (r < 8192) { state_h[r] = packh2(h0[2 * r], h0[2 * r + 1]); continue; }
        r -= 8192;
        zpad[r] = 0u;                           // runtime-opaque zero quad
    }
}

// ---------------- K1/K3: f16 MFMA GEMM, 128x128 tile, K=256 ----------------
template<int AMODE, int CMODE>
__global__ __launch_bounds__(256) void gemm16(
    const void* __restrict__ Ap, const half_t* __restrict__ Bt,
    void* __restrict__ Cp, const float* __restrict__ bias, int chunk0)
{
    __shared__ half_t Als[128][40];
    __shared__ half_t Bls[128][40];
    const int tid  = threadIdx.x;
    const int lane = tid & 63, wid = tid >> 6;
    const int wr = wid >> 1, wc = wid & 1;
    const int m0 = blockIdx.x * 128, n0 = blockIdx.y * 128;

    f32x4 acc[4][4] = {};

    for (int kc = 0; kc < 8; ++kc) {
        __syncthreads();
        if (AMODE == 1) {
            const float* A = (const float*)Ap;
            #pragma unroll
            for (int i = 0; i < 4; ++i) {
                int l = tid + i * 256;
                int row = l >> 3, kq = l & 7;
                int m = m0 + row;
                int arow = ((m >> 9) << 11) + chunk0 + (m & 511);
                f32x4 v = *(const f32x4*)(A + (size_t)arow * 256 + kc * 32 + kq * 4);
                uint2 pk;
                pk.x = packh2(v.x, v.y);
                pk.y = packh2(v.z, v.w);
                *reinterpret_cast<uint2*>(&Als[row][kq * 4]) = pk;
            }
        } else {
            const half_t* A = (const half_t*)Ap;
            #pragma unroll
            for (int i = 0; i < 2; ++i) {
                int l = tid + i * 256;
                int row = l >> 2, ko = l & 3;
                half8_t v = *(const half8_t*)(A + (size_t)(m0 + row) * 256 + kc * 32 + ko * 8);
                *reinterpret_cast<half8_t*>(&Als[row][ko * 8]) = v;
            }
        }
        #pragma unroll
        for (int i = 0; i < 2; ++i) {
            int l = tid + i * 256;
            int row = l >> 2, ko = l & 3;
            half8_t v = *(const half8_t*)(Bt + (size_t)(n0 + row) * 256 + kc * 32 + ko * 8);
            *reinterpret_cast<half8_t*>(&Bls[row][ko * 8]) = v;
        }
        __syncthreads();

        half8_t af[4], bf[4];
        #pragma unroll
        for (int mi = 0; mi < 4; ++mi)
            af[mi] = *reinterpret_cast<const half8_t*>(&Als[wr * 64 + mi * 16 + (lane & 15)][(lane >> 4) * 8]);
        #pragma unroll
        for (int ni = 0; ni < 4; ++ni)
            bf[ni] = *reinterpret_cast<const half8_t*>(&Bls[wc * 64 + ni * 16 + (lane & 15)][(lane >> 4) * 8]);
        #pragma unroll
        for (int mi = 0; mi < 4; ++mi)
            #pragma unroll
            for (int ni = 0; ni < 4; ++ni)
                acc[mi][ni] = __builtin_amdgcn_mfma_f32_16x16x32_f16(af[mi], bf[ni], acc[mi][ni], 0, 0, 0);
    }

    #pragma unroll
    for (int mi = 0; mi < 4; ++mi) {
        #pragma unroll
        for (int ni = 0; ni < 4; ++ni) {
            #pragma unroll
            for (int reg = 0; reg < 4; ++reg) {
                int row = m0 + wr * 64 + mi * 16 + (lane >> 4) * 4 + reg;   // m
                int col = n0 + wc * 64 + ni * 16 + (lane & 15);             // n
                float v = acc[mi][ni][reg] + bias[col];
                if (CMODE == 0) {
                    ((half_t*)Cp)[(size_t)row * 1024 + ((col & 255) << 2) + (col >> 8)] = (half_t)v;
                } else {
                    int crow = ((row >> 9) << 11) + chunk0 + (row & 511);
                    ((float*)Cp)[(size_t)crow * 256 + col] = v;
                }
            }
        }
    }
}

// ---------------- K2: per-chain recurrent LSTM, K-split across 512 threads ----------------
// thread (e = t&255, hh = t>>8): all 4 gate cols of element e, k-half hh.
// 36 weight quads held in a plain fully-unrolled VGPR array. No inline asm anywhere
// (asm presence appears to trigger the unified-file VGPR/AGPR split capping arch VGPRs
// at 128). Values are made non-rematerializable by xor with a runtime-opaque zero quad.
// amdgpu_waves_per_eu(2,2) fixes the occupancy target -> full 256-VGPR budget.
#define W_A(F) F(0) F(1) F(2) F(3) F(4) F(5) F(6) F(7) F(8) F(9) F(10) F(11) \
               F(12) F(13) F(14) F(15) F(16) F(17)
#define W_B(F) F(18) F(19) F(20) F(21) F(22) F(23) F(24) F(25) F(26) F(27) F(28) F(29) \
               F(30) F(31) F(32) F(33) F(34) F(35)
#define W_ALL(F) W_A(F) W_B(F)

#define DOTW(i) { unsigned int s = rlane(hv, (i)); \
    a0 = dot2f(s, wreg[i].x, a0); a1 = dot2f(s, wreg[i].y, a1); \
    a2 = dot2f(s, wreg[i].z, a2); a3 = dot2f(s, wreg[i].w, a3); }
#define DOTQ(i, q) { unsigned int s = rlane(hv, KP_RF + (i)); \
    a0 = dot2f(s, (q).x, a0); a1 = dot2f(s, (q).y, a1); \
    a2 = dot2f(s, (q).z, a2); a3 = dot2f(s, (q).w, a3); }
#define DOTS(i, q) { unsigned int s = rlane(hv, KP_RF + KP_LDS + (i)); \
    a0 = dot2f(s, (q).x, a0); a1 = dot2f(s, (q).y, a1); \
    a2 = dot2f(s, (q).z, a2); a3 = dot2f(s, (q).w, a3); }

__global__
__attribute__((amdgpu_flat_work_group_size(512, 512), amdgpu_waves_per_eu(2, 2)))
void rnn_kernel(
    const uint4v* __restrict__ whh_rf,
    const uint4v* __restrict__ whh_ldsrc,
    const uint4v* __restrict__ whh_str,
    const half_t* __restrict__ xw,
    half_t* __restrict__ h_out,
    float* __restrict__ state_c,
    unsigned int* __restrict__ state_h,
    const uint4v* __restrict__ zq)
{
    __shared__ uint4v lds_w[2 * KP_LDS * 256];   // 131072 B
    __shared__ f32x4  gbuf[256];                 // 4096 B
    __shared__ unsigned int hbuf[128];           // 512 B

    const int t    = threadIdx.x;
    const int e    = t & 255;
    const int hh   = t >> 8;
    const int lane = t & 63;
    const int b    = blockIdx.x;

    for (int i = t; i < 2 * KP_LDS * 256; i += 512) lds_w[i] = whh_ldsrc[i];
    if (t < 128) hbuf[t] = state_h[b * 128 + t];
    float c = (hh == 0) ? state_c[b * 256 + e] : 0.0f;

    // register-resident Whh: k-pairs (hh*64 + 0..35), one uint4 = 4 gate cols {e,256+e,512+e,768+e}
    // xor with runtime zero makes each value a 2-op chain from memory -> not remat'able/sinkable.
    const uint4v z = *zq;
    const uint4v* wq = whh_rf + (size_t)hh * (KP_RF * 256) + e;
    uint4v wreg[KP_RF];
    #pragma unroll
    for (int pl = 0; pl < KP_RF; ++pl) wreg[pl] = wq[pl * 256] ^ z;
    __syncthreads();

    const half_t* xwp = xw + (size_t)b * T_CH * 1024 + e * 4;
    half_t* hop = h_out + (size_t)b * T_CH * 256 + e;
    const uint4v* strq = whh_str + ((size_t)hh * 256 + e) * KP_STR;   // 12 contiguous quads
    const uint4v* ldp  = lds_w + hh * (KP_LDS * 256) + e;

    #pragma unroll 1
    for (int step = 0; step < T_CH; ++step) {
        // h broadcast source: pairs hh*64 .. hh*64+63 (one LDS word per lane)
        unsigned int hv = hbuf[hh * 64 + lane];

        uint2 xv; xv.x = 0; xv.y = 0;
        if (hh == 0) xv = *(const uint2*)xwp;

        float a0 = 0.f, a1 = 0.f, a2 = 0.f, a3 = 0.f;

        // ---- batch 1: 8 LDS + 6 streamed quads (56 transient VGPRs) ----
        {
            uint4v q0 = ldp[0],    q1 = ldp[256],  q2 = ldp[512],  q3 = ldp[768];
            uint4v q4 = ldp[1024], q5 = ldp[1280], q6 = ldp[1536], q7 = ldp[1792];
            uint4v t0 = strq[0], t1 = strq[1], t2 = strq[2];
            uint4v t3 = strq[3], t4 = strq[4], t5 = strq[5];

            W_A(DOTW)   // 72 dots cover batch-1 latency

            DOTQ(0, q0) DOTQ(1, q1) DOTQ(2, q2) DOTQ(3, q3)
            DOTQ(4, q4) DOTQ(5, q5) DOTQ(6, q6) DOTQ(7, q7)
            DOTS(0, t0) DOTS(1, t1) DOTS(2, t2)
            DOTS(3, t3) DOTS(4, t4) DOTS(5, t5)
        }

        // ---- batch 2: remaining 8 LDS + 6 streamed quads ----
        {
            uint4v q8  = ldp[2048], q9  = ldp[2304], q10 = ldp[2560], q11 = ldp[2816];
            uint4v q12 = ldp[3072], q13 = ldp[3328], q14 = ldp[3584], q15 = ldp[3840];
            uint4v t6 = strq[6], t7 = strq[7], t8 = strq[8];
            uint4v t9 = strq[9], t10 = strq[10], t11 = strq[11];

            W_B(DOTW)   // 72 dots cover batch-2 latency

            DOTQ(8, q8)   DOTQ(9, q9)   DOTQ(10, q10) DOTQ(11, q11)
            DOTQ(12, q12) DOTQ(13, q13) DOTQ(14, q14) DOTQ(15, q15)
            DOTS(6, t6)   DOTS(7, t7)   DOTS(8, t8)
            DOTS(9, t9)   DOTS(10, t10) DOTS(11, t11)
        }

        if (hh) {
            f32x4 p; p[0] = a0; p[1] = a1; p[2] = a2; p[3] = a3;
            gbuf[e] = p;
        }
        __syncthreads();   // gbuf write -> read; hbuf read -> write

        half_t h16 = (half_t)0.f;
        if (hh == 0) {
            f32x4 p = gbuf[e];
            half2_t x0 = __builtin_bit_cast(half2_t, xv.x);
            half2_t x1 = __builtin_bit_cast(half2_t, xv.y);
            a0 += p[0] + (float)x0.x;
            a1 += p[1] + (float)x0.y;
            a2 += p[2] + (float)x1.x;
            a3 += p[3] + (float)x1.y;
            float ig = sigm(a0), fg = sigm(a1), gg = tanh_(a2), og = sigm(a3);
            c = fg * c + ig * gg;
            float hn = og * tanh_(c);
            h16 = (half_t)hn;
            reinterpret_cast<half_t*>(hbuf)[e] = h16;
        }
        xwp += 1024;
        __syncthreads();   // hbuf write -> next read; gbuf read -> next write

        // deferred global store: drains at NEXT step's first barrier, off the critical path
        if (hh == 0) *hop = h16;
        hop += 256;
    }

    if (hh == 0) state_c[b * 256 + e] = c;
    if (t < 128) state_h[b * 128 + t] = hbuf[t];
}

// ---------------- launch ----------------
extern "C" void kernel_launch(void* const* d_in, const int* in_sizes, int n_in,
                              void* d_out, int out_size, void* d_ws, size_t ws_size,
                              hipStream_t stream) {
    const float* x    = (const float*)d_in[0];
    const float* c0   = (const float*)d_in[1];
    const float* h0   = (const float*)d_in[2];
    const float* Wih  = (const float*)d_in[3];
    const float* Whh  = (const float*)d_in[4];
    const float* bh   = (const float*)d_in[5];
    const float* Wout = (const float*)d_in[6];
    const float* bout = (const float*)d_in[7];

    char* ws = (char*)d_ws;
    half_t* xw             = (half_t*)(ws + OFF_XW);
    half_t* h_chunk        = (half_t*)(ws + OFF_H);
    half_t* wih_t          = (half_t*)(ws + OFF_WIH);
    half_t* wout_t         = (half_t*)(ws + OFF_WOUT);
    unsigned int* whh_rf   = (unsigned int*)(ws + OFF_WRF);
    unsigned int* whh_lds  = (unsigned int*)(ws + OFF_WLDS);
    unsigned int* whh_str  = (unsigned int*)(ws + OFF_WSTR);
    float* state_c         = (float*)(ws + OFF_SC);
    unsigned int* state_h  = (unsigned int*)(ws + OFF_SH);
    unsigned int* zpad     = (unsigned int*)(ws + OFF_Z);

    pack_kernel<<<512, 256, 0, stream>>>(Wih, Whh, Wout, c0, h0,
                                         wih_t, wout_t, whh_rf, whh_lds, whh_str,
                                         state_c, state_h, zpad);

    for (int ch = 0; ch < N_CHUNK; ++ch) {
        int chunk0 = ch * T_CH;
        gemm16<1, 0><<<dim3(CH_M / 128, G4 / 128), 256, 0, stream>>>(
            (const void*)x, wih_t, (void*)xw, bh, chunk0);
        rnn_kernel<<<B_SZ, 512, 0, stream>>>((const uint4v*)(ws + OFF_WRF),
                                             (const uint4v*)(ws + OFF_WLDS),
                                             (const uint4v*)(ws + OFF_WSTR),
                                             xw, h_chunk, state_c, state_h,
                                             (const uint4v*)(ws + OFF_Z));
        gemm16<0, 1><<<dim3(CH_M / 128, H_SZ / 128), 256, 0, stream>>>(
            (const void*)h_chunk, wout_t, d_out, bout, chunk0);
    }
    (void)in_sizes; (void)n_in; (void)out_size; (void)ws_size;
}

// Round 5
// 3838.683 us; speedup vs baseline: 1.1088x; 1.0907x over previous
//
#include <hip/hip_runtime.h>
#include <hip/hip_fp16.h>
#include <cstdint>
#include <cstddef>

typedef _Float16 half_t;
typedef _Float16 half2_t __attribute__((ext_vector_type(2)));
typedef _Float16 half8_t __attribute__((ext_vector_type(8)));
typedef float    f32x4   __attribute__((ext_vector_type(4)));
typedef unsigned int uint4v __attribute__((ext_vector_type(4)));

#define T_FULL  2048
#define T_CH    512
#define N_CHUNK 4
#define B_SZ    64
#define H_SZ    256
#define G4      1024
#define CH_M    (B_SZ * T_CH)   // 32768

// ---------------- workspace layout (bytes) ----------------
static constexpr size_t OFF_XW   = 0;                                   // half [CH_M][1024] (i,f,g,o)x256
static constexpr size_t OFF_H    = OFF_XW   + (size_t)CH_M * G4 * 2;    // half [CH_M][256]
static constexpr size_t OFF_WIH  = OFF_H    + (size_t)CH_M * H_SZ * 2;  // half [1024][256]  (B^T)
static constexpr size_t OFF_WOUT = OFF_WIH  + (size_t)G4 * 256 * 2;     // half [256][256]   (B^T)
static constexpr size_t OFF_WMF  = OFF_WOUT + (size_t)256 * 256 * 2;    // uint4 frag[8][64][64]  (MFMA B-frags)
static constexpr size_t OFF_SC   = OFF_WMF  + (size_t)8 * 64 * 64 * 16; // float [64][256]
static constexpr size_t OFF_SH   = OFF_SC   + (size_t)B_SZ * H_SZ * 4;  // uint [64][128] f16 pairs

// ---------------- helpers ----------------
__device__ __forceinline__ unsigned int packh2(float a, float b) {
    half2_t h; h.x = (half_t)a; h.y = (half_t)b;
    return __builtin_bit_cast(unsigned int, h);
}

__device__ __forceinline__ float sigm(float x)  { return 1.0f / (1.0f + __expf(-x)); }
__device__ __forceinline__ float tanh_(float x) { return 1.0f - 2.0f / (__expf(2.0f * x) + 1.0f); }

// ---------------- K0: pack weights + init state ----------------
// word sections: wih 262144 | wout 65536 | mf 131072 | c 16384 | h 8192
static constexpr int PACK_TOTAL = 262144 + 65536 + 131072 + 16384 + 8192;

__global__ __launch_bounds__(256) void pack_kernel(
    const float* __restrict__ Wih, const float* __restrict__ Whh,
    const float* __restrict__ Wout, const float* __restrict__ c0,
    const float* __restrict__ h0,
    half_t* __restrict__ wih_t, half_t* __restrict__ wout_t,
    unsigned int* __restrict__ whh_mf,
    float* __restrict__ state_c, unsigned int* __restrict__ state_h)
{
    const int stride = gridDim.x * blockDim.x;
    for (int idx = blockIdx.x * blockDim.x + threadIdx.x; idx < PACK_TOTAL; idx += stride) {
        int r = idx;
        if (r < 262144) {                       // wih_t[n][k] = Wih[k][n]
            int n = r >> 8, k = r & 255;
            wih_t[r] = (half_t)Wih[k * 1024 + n];
            continue;
        }
        r -= 262144;
        if (r < 65536) {                        // wout_t[n][k] = Wout[k][n]
            int n = r >> 8, k = r & 255;
            wout_t[r] = (half_t)Wout[k * 256 + n];
            continue;
        }
        r -= 65536;
        if (r < 131072) {                       // MFMA B-frags: frag[kt][nt][lane], 4 words each
            int j    = r & 3;                   // word within frag (k pair 2j,2j+1)
            int lane = (r >> 2) & 63;
            int nt   = (r >> 8) & 63;
            int kt   = r >> 14;
            int k0 = kt * 32 + ((lane >> 4) << 3) + 2 * j;
            int n  = nt * 16 + (lane & 15);
            whh_mf[r] = packh2(Whh[k0 * 1024 + n], Whh[(k0 + 1) * 1024 + n]);
            continue;
        }
        r -= 131072;
        if (r < 16384) { state_c[r] = c0[r]; continue; }
        r -= 16384;
        state_h[r] = packh2(h0[2 * r], h0[2 * r + 1]);
    }
}

// ---------------- K1/K3: f16 MFMA GEMM, 128x128 tile, K=256 ----------------
template<int AMODE, int CMODE>
__global__ __launch_bounds__(256) void gemm16(
    const void* __restrict__ Ap, const half_t* __restrict__ Bt,
    void* __restrict__ Cp, const float* __restrict__ bias, int chunk0)
{
    __shared__ half_t Als[128][40];
    __shared__ half_t Bls[128][40];
    const int tid  = threadIdx.x;
    const int lane = tid & 63, wid = tid >> 6;
    const int wr = wid >> 1, wc = wid & 1;
    const int m0 = blockIdx.x * 128, n0 = blockIdx.y * 128;

    f32x4 acc[4][4] = {};

    for (int kc = 0; kc < 8; ++kc) {
        __syncthreads();
        if (AMODE == 1) {
            const float* A = (const float*)Ap;
            #pragma unroll
            for (int i = 0; i < 4; ++i) {
                int l = tid + i * 256;
                int row = l >> 3, kq = l & 7;
                int m = m0 + row;
                int arow = ((m >> 9) << 11) + chunk0 + (m & 511);
                f32x4 v = *(const f32x4*)(A + (size_t)arow * 256 + kc * 32 + kq * 4);
                uint2 pk;
                pk.x = packh2(v.x, v.y);
                pk.y = packh2(v.z, v.w);
                *reinterpret_cast<uint2*>(&Als[row][kq * 4]) = pk;
            }
        } else {
            const half_t* A = (const half_t*)Ap;
            #pragma unroll
            for (int i = 0; i < 2; ++i) {
                int l = tid + i * 256;
                int row = l >> 2, ko = l & 3;
                half8_t v = *(const half8_t*)(A + (size_t)(m0 + row) * 256 + kc * 32 + ko * 8);
                *reinterpret_cast<half8_t*>(&Als[row][ko * 8]) = v;
            }
        }
        #pragma unroll
        for (int i = 0; i < 2; ++i) {
            int l = tid + i * 256;
            int row = l >> 2, ko = l & 3;
            half8_t v = *(const half8_t*)(Bt + (size_t)(n0 + row) * 256 + kc * 32 + ko * 8);
            *reinterpret_cast<half8_t*>(&Bls[row][ko * 8]) = v;
        }
        __syncthreads();

        half8_t af[4], bf[4];
        #pragma unroll
        for (int mi = 0; mi < 4; ++mi)
            af[mi] = *reinterpret_cast<const half8_t*>(&Als[wr * 64 + mi * 16 + (lane & 15)][(lane >> 4) * 8]);
        #pragma unroll
        for (int ni = 0; ni < 4; ++ni)
            bf[ni] = *reinterpret_cast<const half8_t*>(&Bls[wc * 64 + ni * 16 + (lane & 15)][(lane >> 4) * 8]);
        #pragma unroll
        for (int mi = 0; mi < 4; ++mi)
            #pragma unroll
            for (int ni = 0; ni < 4; ++ni)
                acc[mi][ni] = __builtin_amdgcn_mfma_f32_16x16x32_f16(af[mi], bf[ni], acc[mi][ni], 0, 0, 0);
    }

    #pragma unroll
    for (int mi = 0; mi < 4; ++mi) {
        #pragma unroll
        for (int ni = 0; ni < 4; ++ni) {
            #pragma unroll
            for (int reg = 0; reg < 4; ++reg) {
                int row = m0 + wr * 64 + mi * 16 + (lane >> 4) * 4 + reg;   // m
                int col = n0 + wc * 64 + ni * 16 + (lane & 15);             // n
                float v = acc[mi][ni][reg] + bias[col];
                if (CMODE == 0) {
                    ((half_t*)Cp)[(size_t)row * 1024 + ((col & 255) << 2) + (col >> 8)] = (half_t)v;
                } else {
                    int crow = ((row >> 9) << 11) + chunk0 + (row & 511);
                    ((float*)Cp)[(size_t)crow * 256 + col] = v;
                }
            }
        }
    }
}

// ---------------- K2: per-chain recurrent LSTM via MFMA (M=1) ----------------
// 64 blocks (one batch chain each), 512 threads = 8 waves. Per step:
// gates[1024] = h[256] x Whh  via mfma_f32_16x16x32_f16, M=1 (A rows 1-15 zeroed).
// Wave w owns N-tiles w*8..w*8+7. K-tiles: 0-3 register/AGPR-resident B-frags
// (MFMA reads AGPRs natively -> no residency fight), 4-5 staged in LDS (128 KB),
// 6-7 streamed from L2 each step (loop-invariant addresses, ~64KB/CU/step).
__global__ __launch_bounds__(512) void rnn_kernel(
    const uint4v* __restrict__ whh_mf,
    const half_t* __restrict__ xw,
    half_t* __restrict__ h_out,
    float* __restrict__ state_c,
    unsigned int* __restrict__ state_h)
{
    __shared__ uint4v lds_b[2 * 4096];       // B-frags kt 4,5: 131072 B
    __shared__ float  gbuf[1024];            // 4096 B
    __shared__ unsigned int hbuf[128];       // 512 B = h as 256 f16

    const int t    = threadIdx.x;
    const int lane = t & 63;
    const int w    = t >> 6;
    const int e    = t & 255;                // update element (threads 0..255)
    const int b    = blockIdx.x;

    for (int i = t; i < 8192; i += 512) lds_b[i] = whh_mf[4 * 4096 + i];
    if (t < 128) hbuf[t] = state_h[b * 128 + t];
    float c = (t < 256) ? state_c[b * 256 + e] : 0.0f;

    // resident B-frags: kt 0..3, this wave's 8 N-tiles (128 regs -> VGPR/AGPR)
    const half8_t* mf8 = (const half8_t*)whh_mf;
    half8_t Bres[4][8];
    #pragma unroll
    for (int r = 0; r < 4; ++r)
        #pragma unroll
        for (int ntl = 0; ntl < 8; ++ntl)
            Bres[r][ntl] = mf8[(r * 64 + w * 8 + ntl) * 64 + lane];
    __syncthreads();

    const half_t* xwp = xw + (size_t)b * T_CH * 1024 + e * 4;
    half_t* hop = h_out + (size_t)b * T_CH * 256 + e;
    const half_t* hbh = (const half_t*)hbuf;

    #pragma unroll 1
    for (int step = 0; step < T_CH; ++step) {
        uint2 xv; xv.x = 0; xv.y = 0;
        if (t < 256) xv = *(const uint2*)xwp;

        // A-frags: row 0 = h (lanes with lane&15==0 carry k-chunks), rows 1-15 zero
        half8_t a[8];
        #pragma unroll
        for (int kt = 0; kt < 8; ++kt) {
            half8_t v = {};
            if ((lane & 15) == 0)
                v = *(const half8_t*)(hbh + kt * 32 + (lane >> 4) * 8);
            a[kt] = v;
        }

        #pragma unroll
        for (int ntl = 0; ntl < 8; ++ntl) {
            const int nt = w * 8 + ntl;
            half8_t l4 = *(const half8_t*)&lds_b[0 * 4096 + nt * 64 + lane];
            half8_t l5 = *(const half8_t*)&lds_b[1 * 4096 + nt * 64 + lane];
            half8_t g6 = mf8[(6 * 64 + nt) * 64 + lane];
            half8_t g7 = mf8[(7 * 64 + nt) * 64 + lane];
            f32x4 cc = {};
            cc = __builtin_amdgcn_mfma_f32_16x16x32_f16(a[0], Bres[0][ntl], cc, 0, 0, 0);
            cc = __builtin_amdgcn_mfma_f32_16x16x32_f16(a[1], Bres[1][ntl], cc, 0, 0, 0);
            cc = __builtin_amdgcn_mfma_f32_16x16x32_f16(a[2], Bres[2][ntl], cc, 0, 0, 0);
            cc = __builtin_amdgcn_mfma_f32_16x16x32_f16(a[3], Bres[3][ntl], cc, 0, 0, 0);
            cc = __builtin_amdgcn_mfma_f32_16x16x32_f16(a[4], l4, cc, 0, 0, 0);
            cc = __builtin_amdgcn_mfma_f32_16x16x32_f16(a[5], l5, cc, 0, 0, 0);
            cc = __builtin_amdgcn_mfma_f32_16x16x32_f16(a[6], g6, cc, 0, 0, 0);
            cc = __builtin_amdgcn_mfma_f32_16x16x32_f16(a[7], g7, cc, 0, 0, 0);
            // C row 0 lives in lanes 0-15, reg 0
            if (lane < 16) gbuf[nt * 16 + lane] = cc[0];
        }
        __syncthreads();   // gbuf writes -> update reads; hbuf reads -> update write

        half_t h16 = (half_t)0.f;
        if (t < 256) {
            half2_t x0 = __builtin_bit_cast(half2_t, xv.x);
            half2_t x1 = __builtin_bit_cast(half2_t, xv.y);
            float a0 = gbuf[e]       + (float)x0.x;
            float a1 = gbuf[256 + e] + (float)x0.y;
            float a2 = gbuf[512 + e] + (float)x1.x;
            float a3 = gbuf[768 + e] + (float)x1.y;
            float ig = sigm(a0), fg = sigm(a1), gg = tanh_(a2), og = sigm(a3);
            c = fg * c + ig * gg;
            float hn = og * tanh_(c);
            h16 = (half_t)hn;
            ((half_t*)hbuf)[e] = h16;
        }
        xwp += 1024;
        __syncthreads();   // hbuf write -> next A-read; gbuf read -> next write

        // deferred global store: drains at NEXT step's barrier, off the critical path
        if (t < 256) *hop = h16;
        hop += 256;
    }

    if (t < 256) state_c[b * 256 + e] = c;
    if (t < 128) state_h[b * 128 + t] = hbuf[t];
}

// ---------------- launch ----------------
extern "C" void kernel_launch(void* const* d_in, const int* in_sizes, int n_in,
                              void* d_out, int out_size, void* d_ws, size_t ws_size,
                              hipStream_t stream) {
    const float* x    = (const float*)d_in[0];
    const float* c0   = (const float*)d_in[1];
    const float* h0   = (const float*)d_in[2];
    const float* Wih  = (const float*)d_in[3];
    const float* Whh  = (const float*)d_in[4];
    const float* bh   = (const float*)d_in[5];
    const float* Wout = (const float*)d_in[6];
    const float* bout = (const float*)d_in[7];

    char* ws = (char*)d_ws;
    half_t* xw             = (half_t*)(ws + OFF_XW);
    half_t* h_chunk        = (half_t*)(ws + OFF_H);
    half_t* wih_t          = (half_t*)(ws + OFF_WIH);
    half_t* wout_t         = (half_t*)(ws + OFF_WOUT);
    unsigned int* whh_mf   = (unsigned int*)(ws + OFF_WMF);
    float* state_c         = (float*)(ws + OFF_SC);
    unsigned int* state_h  = (unsigned int*)(ws + OFF_SH);

    pack_kernel<<<512, 256, 0, stream>>>(Wih, Whh, Wout, c0, h0,
                                         wih_t, wout_t, whh_mf,
                                         state_c, state_h);

    for (int ch = 0; ch < N_CHUNK; ++ch) {
        int chunk0 = ch * T_CH;
        gemm16<1, 0><<<dim3(CH_M / 128, G4 / 128), 256, 0, stream>>>(
            (const void*)x, wih_t, (void*)xw, bh, chunk0);
        rnn_kernel<<<B_SZ, 512, 0, stream>>>((const uint4v*)(ws + OFF_WMF),
                                             xw, h_chunk, state_c, state_h);
        gemm16<0, 1><<<dim3(CH_M / 128, H_SZ / 128), 256, 0, stream>>>(
            (const void*)h_chunk, wout_t, d_out, bout, chunk0);
    }
    (void)in_sizes; (void)n_in; (void)out_size; (void)ws_size;
}